// Round 2
// baseline (1502.404 us; speedup 1.0000x reference)
//
#include <hip/hip_runtime.h>

#define N_NODES 100000
#define N_EDGES 1600000
#define IN_F 128
#define OUT_F 64
#define ROWS 32   // rows per GEMM block

// Kernel 1: support = X @ W  (fp32 vector ALU — no fp32 MFMA on CDNA4).
// Block = 256 threads computes a 32x64 tile; each thread does 8 row-outputs of
// one column. Weight (32 KB) + 32 x-rows (16 KB) in LDS = 48 KB -> 3 blocks/CU.
// Also initializes out[row][col] = bias[col] for the scatter pass.
__global__ __launch_bounds__(256) void gemm_bias_kernel(
    const float* __restrict__ x, const float* __restrict__ w,
    const float* __restrict__ bias,
    float* __restrict__ support, float* __restrict__ out) {
    __shared__ float w_lds[IN_F * OUT_F];   // 32 KB
    __shared__ float x_lds[ROWS * IN_F];    // 16 KB

    const int t = threadIdx.x;
    // Stage weight: 8192 floats = 2048 float4 / 256 threads = 8 each.
    {
        const float4* w4 = (const float4*)w;
        float4* wl4 = (float4*)w_lds;
        #pragma unroll
        for (int i = 0; i < 8; ++i) wl4[t + 256 * i] = w4[t + 256 * i];
    }
    // Stage 32 rows of x: 4096 floats = 1024 float4 / 256 threads = 4 each.
    {
        const float4* x4 = (const float4*)(x + (size_t)blockIdx.x * ROWS * IN_F);
        float4* xl4 = (float4*)x_lds;
        #pragma unroll
        for (int i = 0; i < 4; ++i) xl4[t + 256 * i] = x4[t + 256 * i];
    }
    __syncthreads();

    const int col = t & 63;
    const int rg  = t >> 6;   // wave id in block: rows rg*8 .. rg*8+7

    float acc[8] = {0.f, 0.f, 0.f, 0.f, 0.f, 0.f, 0.f, 0.f};
    #pragma unroll 4
    for (int k4 = 0; k4 < IN_F / 4; ++k4) {
        const int k = k4 * 4;
        // stride-1 across lanes -> 2-way bank alias (free on gfx950)
        const float w0 = w_lds[(k + 0) * OUT_F + col];
        const float w1 = w_lds[(k + 1) * OUT_F + col];
        const float w2 = w_lds[(k + 2) * OUT_F + col];
        const float w3 = w_lds[(k + 3) * OUT_F + col];
        #pragma unroll
        for (int j = 0; j < 8; ++j) {
            // same address across the wave -> LDS broadcast (conflict-free)
            const float4 xv = *(const float4*)&x_lds[(rg * 8 + j) * IN_F + k];
            acc[j] += xv.x * w0 + xv.y * w1 + xv.z * w2 + xv.w * w3;
        }
    }

    const float b = bias[col];
    const size_t base = (size_t)blockIdx.x * ROWS * OUT_F;
    #pragma unroll
    for (int j = 0; j < 8; ++j) {
        const size_t idx = base + (size_t)(rg * 8 + j) * OUT_F + col;
        support[idx] = acc[j];
        out[idx] = b;
    }
}

// Kernel 2: COO scatter-add, persistent grid-stride waves.
// Per wave-iteration: 16 edges. Lane = sub*16 + q; each 16-lane group (sub)
// owns 4 edges (u-loop), lane covers feature quad q via float4.
// 4 independent float4 gathers in flight -> hides HBM latency.
__global__ __launch_bounds__(256) void scatter_kernel(
    const float* __restrict__ support,
    const int* __restrict__ erow, const int* __restrict__ ecol,
    const float* __restrict__ evals, float* __restrict__ out) {
    const int wid  = (blockIdx.x * 256 + threadIdx.x) >> 6;
    const int nw   = gridDim.x * 4;
    const int lane = threadIdx.x & 63;
    const int sub  = lane >> 4;       // 0..3
    const int qoff = (lane & 15) * 4; // feature quad offset

    const int n_iters = N_EDGES / 16;   // 100000
    for (int it = wid; it < n_iters; it += nw) {
        const int e0 = it * 16 + sub;
        int src[4], dst[4];
        float val[4];
        #pragma unroll
        for (int u = 0; u < 4; ++u) {
            const int e = e0 + u * 4;   // 4 consecutive ints across sub -> coalesced
            src[u] = ecol[e];
            dst[u] = erow[e];
            val[u] = evals[e];
        }
        float4 g[4];
        #pragma unroll
        for (int u = 0; u < 4; ++u) {
            g[u] = *(const float4*)&support[(size_t)src[u] * OUT_F + qoff];
        }
        #pragma unroll
        for (int u = 0; u < 4; ++u) {
            float* o = &out[(size_t)dst[u] * OUT_F + qoff];
            atomicAdd(o + 0, g[u].x * val[u]);
            atomicAdd(o + 1, g[u].y * val[u]);
            atomicAdd(o + 2, g[u].z * val[u]);
            atomicAdd(o + 3, g[u].w * val[u]);
        }
    }
}

extern "C" void kernel_launch(void* const* d_in, const int* in_sizes, int n_in,
                              void* d_out, int out_size, void* d_ws, size_t ws_size,
                              hipStream_t stream) {
    const float* x     = (const float*)d_in[0];
    const float* w     = (const float*)d_in[1];
    const float* bias  = (const float*)d_in[2];
    const int* erow    = (const int*)d_in[3];
    const int* ecol    = (const int*)d_in[4];
    const float* evals = (const float*)d_in[5];
    float* out = (float*)d_out;
    float* support = (float*)d_ws;   // 100000*64*4 = 25.6 MB

    gemm_bias_kernel<<<N_NODES / ROWS, 256, 0, stream>>>(x, w, bias, support, out);

    // 2048 blocks * 4 waves = 8192 persistent waves; ~12 iters each.
    scatter_kernel<<<2048, 256, 0, stream>>>(support, erow, ecol, evals, out);
}

// Round 3
// 492.406 us; speedup vs baseline: 3.0512x; 3.0512x over previous
//
#include <hip/hip_runtime.h>

#define N_NODES 100000
#define N_EDGES 1600000
#define IN_F 128
#define OUT_F 64
#define ROWS 32   // rows per GEMM block
#define EB 8      // edges per scatter wave-iteration

// Kernel 1: support = X @ W  (fp32 vector ALU — no fp32 MFMA on CDNA4).
// Block = 256 threads = 4 waves; each wave computes 8 rows x 64 cols.
// W (32 KB) in LDS, read stride-1 (2-way alias = free). X rows are wave-uniform
// -> readfirstlane'd base so the compiler emits scalar (SMEM) loads; x never
// touches LDS. Also initializes out[row][col] = bias[col].
__global__ __launch_bounds__(256) void gemm_bias_kernel(
    const float* __restrict__ x, const float* __restrict__ w,
    const float* __restrict__ bias,
    float* __restrict__ support, float* __restrict__ out) {
    __shared__ float w_lds[IN_F * OUT_F];   // 32 KB

    const int t = threadIdx.x;
    {   // Stage weight: 2048 float4 / 256 threads = 8 each.
        const float4* w4 = (const float4*)w;
        float4* wl4 = (float4*)w_lds;
        #pragma unroll
        for (int i = 0; i < 8; ++i) wl4[t + 256 * i] = w4[t + 256 * i];
    }
    __syncthreads();

    const int col = t & 63;
    const int rg  = t >> 6;   // wave id: rows rg*8 .. rg*8+7
    // wave-uniform row base -> scalar loads for x
    const int row0 = __builtin_amdgcn_readfirstlane(blockIdx.x * ROWS + rg * 8);
    const float* xb = x + (size_t)row0 * IN_F;

    float acc[8] = {0.f, 0.f, 0.f, 0.f, 0.f, 0.f, 0.f, 0.f};
    #pragma unroll 2
    for (int k = 0; k < IN_F; k += 4) {
        const float w0 = w_lds[(k + 0) * OUT_F + col];
        const float w1 = w_lds[(k + 1) * OUT_F + col];
        const float w2 = w_lds[(k + 2) * OUT_F + col];
        const float w3 = w_lds[(k + 3) * OUT_F + col];
        #pragma unroll
        for (int j = 0; j < 8; ++j) {
            const float x0 = xb[j * IN_F + k + 0];
            const float x1 = xb[j * IN_F + k + 1];
            const float x2 = xb[j * IN_F + k + 2];
            const float x3 = xb[j * IN_F + k + 3];
            acc[j] += x0 * w0 + x1 * w1 + x2 * w2 + x3 * w3;
        }
    }

    const float b = bias[col];
    const size_t base = (size_t)row0 * OUT_F;
    #pragma unroll
    for (int j = 0; j < 8; ++j) {
        const size_t idx = base + (size_t)j * OUT_F + col;
        support[idx] = acc[j];
        out[idx] = b;
    }
}

// Kernel 2: COO scatter-add, persistent waves, EB edges per iteration.
// lane = feature index. Per edge: 64-lane gather of 256B (coalesced) and ONE
// wave-wide atomic instruction over 64 consecutive floats -> L2 coalesces each
// 64B line into a single RMW (this was the R2 regression: split atomics = 4x
// line traffic). EB independent gathers per iteration hide load latency.
__global__ __launch_bounds__(256) void scatter_kernel(
    const float* __restrict__ support,
    const int* __restrict__ erow, const int* __restrict__ ecol,
    const float* __restrict__ evals, float* __restrict__ out) {
    const int wid  = (blockIdx.x * 256 + threadIdx.x) >> 6;
    const int nw   = gridDim.x * 4;
    const int lane = threadIdx.x & 63;

    const int n_iters = N_EDGES / EB;   // 200000
    for (int it0 = wid; it0 < n_iters; it0 += nw) {
        const int it = __builtin_amdgcn_readfirstlane(it0);
        const int e0 = it * EB;
        // wave-uniform metadata -> scalar loads
        int src[EB], dst[EB];
        float val[EB];
        #pragma unroll
        for (int u = 0; u < EB; ++u) {
            src[u] = ecol[e0 + u];
            dst[u] = erow[e0 + u];
            val[u] = evals[e0 + u];
        }
        // EB independent coalesced gathers in flight
        float g[EB];
        #pragma unroll
        for (int u = 0; u < EB; ++u) {
            g[u] = support[(size_t)src[u] * OUT_F + lane];
        }
        #pragma unroll
        for (int u = 0; u < EB; ++u) {
            atomicAdd(&out[(size_t)dst[u] * OUT_F + lane], g[u] * val[u]);
        }
    }
}

extern "C" void kernel_launch(void* const* d_in, const int* in_sizes, int n_in,
                              void* d_out, int out_size, void* d_ws, size_t ws_size,
                              hipStream_t stream) {
    const float* x     = (const float*)d_in[0];
    const float* w     = (const float*)d_in[1];
    const float* bias  = (const float*)d_in[2];
    const int* erow    = (const int*)d_in[3];
    const int* ecol    = (const int*)d_in[4];
    const float* evals = (const float*)d_in[5];
    float* out = (float*)d_out;
    float* support = (float*)d_ws;   // 100000*64*4 = 25.6 MB

    gemm_bias_kernel<<<N_NODES / ROWS, 256, 0, stream>>>(x, w, bias, support, out);

    // 2048 blocks * 4 waves = 8192 persistent waves, ~24 iters each.
    scatter_kernel<<<2048, 256, 0, stream>>>(support, erow, ecol, evals, out);
}